// Round 1
// 82.202 us; speedup vs baseline: 1.0498x; 1.0498x over previous
//
#include <hip/hip_runtime.h>
#include <stdint.h>

// SpanNERDecoder: B=4,S=512,D=768,MAX_LEN=10,LEN_EMB=25,C=9, N=S*10=5120
// fp32 in / fp32 out (confirmed in earlier rounds; bf16 either NaN'd or
// produced half-matched output).
// One wave per (b, s0): the 10 spans starting at s0 share a running max-pool
// (lens within a start group are nondecreasing: min(j+1, S-s0)).
//
// This revision vs previous (86.3us measured, kernel ~5.3us of it):
//  - folding 9-value reduce: 21 shfl + 21 add + 8 sel (was 54 shfl + 54 add)
//  - software pipeline: reduce(span j-1) interleaved with dot(span j)
//  - one-row register prefetch ahead of each dot
constexpr int kB = 4, kS = 512, kD = 768, kMaxLen = 10, kLenEmb = 25, kC = 9;
constexpr int kN = kS * kMaxLen;

// Reduce 9 per-lane partials over all 64 lanes. At each xor level the live
// value set halves while different labels migrate to different lane subsets.
// Final full sums land at: lane 0->c0, 8->c1, 4->c2, 2->c3, 10->c4, 1->c5,
// 9->c6, 5->c7, 3->c8 (other lanes hold duplicates/garbage, never read).
__device__ __forceinline__ float reduce9_fold(const float acc[kC], int lane) {
  float s0 = acc[0] + __shfl_xor(acc[0], 1, 64);
  float s1 = acc[1] + __shfl_xor(acc[1], 1, 64);
  float s2 = acc[2] + __shfl_xor(acc[2], 1, 64);
  float s3 = acc[3] + __shfl_xor(acc[3], 1, 64);
  float s4 = acc[4] + __shfl_xor(acc[4], 1, 64);
  float s5 = acc[5] + __shfl_xor(acc[5], 1, 64);
  float s6 = acc[6] + __shfl_xor(acc[6], 1, 64);
  float s7 = acc[7] + __shfl_xor(acc[7], 1, 64);
  float s8 = acc[8] + __shfl_xor(acc[8], 1, 64);
  const bool o1 = (lane & 1) != 0;
  const bool o2 = (lane & 2) != 0;
  const bool o4 = (lane & 4) != 0;
  const bool o8 = (lane & 8) != 0;
  // even lanes carry c0..c4, odd lanes carry c5..c8 (b4: c4 pair-sum, all lanes)
  float b0 = o1 ? s5 : s0;
  float b1 = o1 ? s6 : s1;
  float b2 = o1 ? s7 : s2;
  float b3 = o1 ? s8 : s3;
  float b4 = s4;
  float u0 = b0 + __shfl_xor(b0, 2, 64);
  float u1 = b1 + __shfl_xor(b1, 2, 64);
  float u2 = b2 + __shfl_xor(b2, 2, 64);
  float u3 = b3 + __shfl_xor(b3, 2, 64);
  float u4 = b4 + __shfl_xor(b4, 2, 64);
  float q0 = o2 ? u3 : u0;
  float q1 = o2 ? u4 : u1;
  float q2 = u2;
  float v0 = q0 + __shfl_xor(q0, 4, 64);
  float v1 = q1 + __shfl_xor(q1, 4, 64);
  float v2 = q2 + __shfl_xor(q2, 4, 64);
  float d0 = o4 ? v2 : v0;
  float d1 = v1;
  float w0 = d0 + __shfl_xor(d0, 8, 64);
  float w1 = d1 + __shfl_xor(d1, 8, 64);
  float e0 = o8 ? w1 : w0;
  float f0 = e0 + __shfl_xor(e0, 16, 64);
  return f0 + __shfl_xor(f0, 32, 64);
}

__global__ __launch_bounds__(256) void span_ner_kernel(
    const float* __restrict__ emb,      // B*S*D
    const int* __restrict__ starts,     // (B,N) broadcast rows -> index by n
    const int* __restrict__ lens,       // (B,N) broadcast rows -> index by n
    const float* __restrict__ len_tab,  // MAX_LEN*LEN_EMB
    const float* __restrict__ W,        // (D+LEN_EMB)*C row-major
    const float* __restrict__ bias,     // C
    float* __restrict__ out)            // B*N*C fp32
{
  // lenAdd[L][c] = bias[c] + sum_e len_tab[L][e] * W[768+e][c]  (90 values)
  __shared__ float lenAdd[kMaxLen][kC];
  const int t = threadIdx.x;
  if (t < kMaxLen * kC) {
    const int L = t / kC, c = t % kC;
    float s = bias[c];
    #pragma unroll
    for (int e = 0; e < kLenEmb; ++e)
      s = fmaf(len_tab[L * kLenEmb + e], W[(kD + e) * kC + c], s);
    lenAdd[L][c] = s;
  }
  __syncthreads();

  const int lane = t & 63;
  const int wid  = blockIdx.x * 4 + (t >> 6);  // 0..2047
  const int b    = wid >> 9;
  const int s0   = wid & 511;

  // writer-lane -> label mapping for reduce9_fold's final layout
  int myc = -1;
  switch (lane) {
    case 0:  myc = 0; break;
    case 8:  myc = 1; break;
    case 4:  myc = 2; break;
    case 2:  myc = 3; break;
    case 10: myc = 4; break;
    case 1:  myc = 5; break;
    case 9:  myc = 6; break;
    case 5:  myc = 7; break;
    case 3:  myc = 8; break;
    default: break;
  }

  // W slice for this lane: features [lane*12, lane*12+12), all 9 labels —
  // 108 contiguous floats at lane*108 (432B offset, 16-aligned).
  float w[108];
  {
    const float4* wp = (const float4*)(W + lane * 108);
    #pragma unroll
    for (int i = 0; i < 27; ++i) {
      float4 u = wp[i];
      w[4 * i + 0] = u.x;
      w[4 * i + 1] = u.y;
      w[4 * i + 2] = u.z;
      w[4 * i + 3] = u.w;
    }
  }

  const int base_n = s0 * kMaxLen;

  // All 10 span lens up front (wave-uniform values, clamped as before).
  int lnv[kMaxLen];
  #pragma unroll
  for (int j = 0; j < kMaxLen; ++j) {
    int ln = lens[base_n + j];
    lnv[j] = min(max(ln, 1), kMaxLen);
  }
  const int start = starts[base_n];  // wave-uniform
  const float* rowbase = emb + (size_t)(b * kS + start) * kD + lane * 12;

  float pool[12];
  #pragma unroll
  for (int k = 0; k < 12; ++k) pool[k] = -INFINITY;
  float rn[12];  // one-row register prefetch

  auto loadfold = [&](int r) {
    const float4* rp = (const float4*)(rowbase + (size_t)r * kD);
    #pragma unroll
    for (int i = 0; i < 3; ++i) {
      float4 u = rp[i];
      pool[4 * i + 0] = fmaxf(pool[4 * i + 0], u.x);
      pool[4 * i + 1] = fmaxf(pool[4 * i + 1], u.y);
      pool[4 * i + 2] = fmaxf(pool[4 * i + 2], u.z);
      pool[4 * i + 3] = fmaxf(pool[4 * i + 3], u.w);
    }
  };
  auto loadrn = [&](int r) {
    const float4* rp = (const float4*)(rowbase + (size_t)r * kD);
    #pragma unroll
    for (int i = 0; i < 3; ++i) {
      float4 u = rp[i];
      rn[4 * i + 0] = u.x;
      rn[4 * i + 1] = u.y;
      rn[4 * i + 2] = u.z;
      rn[4 * i + 3] = u.w;
    }
  };
  auto foldrn = [&]() {
    #pragma unroll
    for (int k = 0; k < 12; ++k) pool[k] = fmaxf(pool[k], rn[k]);
  };
  auto dot9 = [&](float acc[kC]) {
    #pragma unroll
    for (int c = 0; c < kC; ++c) acc[c] = 0.f;
    #pragma unroll
    for (int k = 0; k < 12; ++k)
      #pragma unroll
      for (int c = 0; c < kC; ++c)
        acc[c] = fmaf(pool[k], w[k * kC + c], acc[c]);
  };

  int rl = 0;  // rows folded into the running max so far
  // span 0 pool (common case: exactly 1 row)
  while (rl < lnv[0]) { loadfold(rl); ++rl; }
  // prefetch first row for span 1 (if it adds one)
  bool pf = (rl < lnv[1]);
  if (pf) loadrn(rl);

  float accA[kC];
  dot9(accA);  // span 0

  #pragma unroll
  for (int j = 1; j < kMaxLen; ++j) {
    // bring pool up to span j's length (prefetched row + rare extras)
    if (pf) { foldrn(); ++rl; pf = false; }
    while (rl < lnv[j]) { loadfold(rl); ++rl; }
    // issue prefetch for span j+1 before the dot so the load hides under it
    if (j + 1 < kMaxLen) {
      pf = (rl < lnv[j + 1]);
      if (pf) loadrn(rl);
    }
    // dot for span j; reduce+store for span j-1 — same scheduling region so
    // the 6-level shfl chain hides under the 108 independent FMAs.
    float accB[kC];
    dot9(accB);
    float g = reduce9_fold(accA, lane);
    if (myc >= 0) {
      out[(size_t)(b * kN + base_n + (j - 1)) * kC + myc] =
          g + lenAdd[lnv[j - 1] - 1][myc];
    }
    #pragma unroll
    for (int c = 0; c < kC; ++c) accA[c] = accB[c];
  }
  // span 9 epilogue
  {
    float g = reduce9_fold(accA, lane);
    if (myc >= 0) {
      out[(size_t)(b * kN + base_n + (kMaxLen - 1)) * kC + myc] =
          g + lenAdd[lnv[kMaxLen - 1] - 1][myc];
    }
  }
}

extern "C" void kernel_launch(void* const* d_in, const int* in_sizes, int n_in,
                              void* d_out, int out_size, void* d_ws, size_t ws_size,
                              hipStream_t stream) {
  const float* emb     = (const float*)d_in[0];
  const int*   starts  = (const int*)d_in[1];
  const int*   lens    = (const int*)d_in[2];
  const float* len_tab = (const float*)d_in[3];
  const float* W       = (const float*)d_in[4];
  const float* bias    = (const float*)d_in[5];
  float*       out     = (float*)d_out;

  dim3 grid(kB * kS / 4);  // 512 blocks x 256 threads = 2048 waves
  span_ner_kernel<<<grid, dim3(256), 0, stream>>>(emb, starts, lens, len_tab, W,
                                                  bias, out);
}